// Round 5
// baseline (24244.675 us; speedup 1.0000x reference)
//
#include <hip/hip_runtime.h>

// RNNModel: 2-layer LSTM (B=64,T=400,E=H=500) + MLP head (800->100->2).
// Round 5: barrier-free chunk loop (counted vmcnt), 8x8 thread tiles
// (16 FMA per ds_read_b128), source-permuted XOR swizzle for weight LDS.
// See round-4 notes; numerics family unchanged (absmax 0.0 in r1/r2/r3/r4).

#define NBLK 256
#define NTHR 512
#define Bn 64
#define Tn 400
#define Hn 500

#define OFF_H1  0            // float [2][500*64] transposed h1
#define OFF_H2  256000       // float [2][500*64] transposed h2
#define OFF_D1  512000       // float [64*800]
#define OFF_D2  716800       // float [64*100]
#define OFF_FLG 742400       // 256 flags, stride 64 B
#define OFF_GO  758784       // broadcast epoch

__device__ __forceinline__ void gbar(unsigned* flags, unsigned* gop,
                                     int bid, int tid, unsigned ep) {
    __syncthreads();
    if (bid == 0) {
        if (tid >= 1 && tid < NBLK) {
            while (__hip_atomic_load(&flags[tid * 16], __ATOMIC_ACQUIRE,
                                     __HIP_MEMORY_SCOPE_AGENT) < ep)
                __builtin_amdgcn_s_sleep(1);
        }
        __syncthreads();
        if (tid == 0) {
            __threadfence();
            __hip_atomic_store(gop, ep, __ATOMIC_RELEASE, __HIP_MEMORY_SCOPE_AGENT);
        }
    } else {
        if (tid == 0) {
            __threadfence();
            __hip_atomic_store(&flags[bid * 16], ep, __ATOMIC_RELEASE,
                               __HIP_MEMORY_SCOPE_AGENT);
            while (__hip_atomic_load(gop, __ATOMIC_ACQUIRE,
                                     __HIP_MEMORY_SCOPE_AGENT) < ep)
                __builtin_amdgcn_s_sleep(1);
        }
        __syncthreads();
    }
}

extern "C" __global__ void __launch_bounds__(NTHR)
rnn_all(const int* __restrict__ X, const float* __restrict__ embed,
        const float* __restrict__ k1, const float* __restrict__ b1g,
        const float* __restrict__ k2, const float* __restrict__ b2g,
        const float* __restrict__ w1, const float* __restrict__ bw1,
        const float* __restrict__ w2, const float* __restrict__ bw2,
        const float* __restrict__ wpm, const float* __restrict__ bpv,
        float* __restrict__ out, char* __restrict__ ws)
{
    __shared__ float s_x[16384];     // [1024 k][16 b]; rows 1000..1023 stay 0
    __shared__ float s_w[2][8192];   // dbuf [128 rows][64 cols, swizzled]
    // s_P aliases s_w[0]: [w8][64 cl][16 b'] -- wave w's seg == its own rows

    float* h1b = (float*)(ws + OFF_H1);
    float* h2b = (float*)(ws + OFF_H2);
    float* d1p = (float*)(ws + OFF_D1);
    float* d2p = (float*)(ws + OFF_D2);
    unsigned* flags = (unsigned*)(ws + OFF_FLG);
    unsigned* gop = (unsigned*)(ws + OFF_GO);

    const int bid = blockIdx.x;
    const int tid = threadIdx.x;
    const int rr_ = bid >> 3;
    const int slice = (bid & 7) * 8 + (rr_ >> 2);  // XCD-grouped duplicates
    const int btile = rr_ & 3;
    const int L = slice >> 5;
    const int ut = slice & 31;
    const int b0 = btile * 16;

    const int w = tid >> 6;          // wave
    const int l = tid & 63;
    const int ks = l >> 4;           // K sublane 0..3
    const int c8 = (l & 15) >> 1;    // col-group (8 cols)
    const int b2 = l & 1;            // batch half (8 batches)

    const float* Wm = L ? k2 : k1;   // [1000][2000], col = g*500+u
    const float* bv = L ? b2g : b1g;

    // weight gll source mapping (lane l -> permuted col quad; LDS dest linear)
    const int wclq = 4 * ((l & 15) ^ (2 * (l >> 4)) ^ ((l >> 4) & 1));
    const int wuq = min(ut * 16 + (wclq & 15), 496);
    const int wcolg = (wclq >> 4) * 500 + wuq;   // quad stays in-bounds
    const int wri = l >> 4;

    // x gll lane consts
    const int xr4 = l >> 2;
    const int xj = (l & 3) * 4;

    // read-side offsets
    const int wc0 = 8 * (c8 ^ ks) + 4 * (ks & 1);  // pos of logical cols 8c8..+3
    const int wc1 = wc0 ^ 4;                       // pos of logical cols 8c8+4..+7
    const int xoff = b2 * 8;

    // gate-thread consts (tid<256): (batch gb, unit uu)
    const int uu = tid & 15;
    const int gb = tid >> 4;
    const int u = ut * 16 + uu;
    const bool gth = (tid < 256) && (u < Hn);
    const int swb = gb ^ (4 * (uu >> 3));
    const float bg0 = gth ? bv[u] : 0.f;
    const float bg1 = gth ? bv[500 + u] : 0.f;
    const float bg2 = gth ? bv[1000 + u] : 0.f;
    const float bg3 = gth ? bv[1500 + u] : 0.f;
    double cstate = 0.0;

    // zero pad rows 1000..1023 once (never rewritten)
    for (int idx = tid; idx < 384; idx += NTHR) s_x[16000 + idx] = 0.f;

    unsigned ep = 0;

    for (int s = 0; s <= Tn; ++s) {
        const int cur = s & 1, prv = cur ^ 1;
        const float* h1p = h1b + prv * 32000;
        const float* h2p = h2b + prv * 32000;
        float* houtT = (L ? h2b : h1b) + cur * 32000;
        const bool active = L ? (s >= 1) : (s < Tn);

        if (active) {
            const int t = L ? (s - 1) : s;
            // ---------------- x staging ----------------
            if (L == 0) {
                const int eb = tid & 15, q0 = tid >> 4;
                const float* er = embed + (size_t)X[(b0 + eb) * Tn + t] * 500;
                #pragma unroll
                for (int jj = 0; jj < 4; ++jj) {
                    const int q = q0 + 32 * jj;
                    if (q < 125) {
                        const float4 v = *(const float4*)(er + 4 * q);
                        float* d = &s_x[(4 * q) * 16 + eb];
                        d[0] = v.x; d[16] = v.y; d[32] = v.z; d[48] = v.w;
                    }
                }
                #pragma unroll
                for (int q = 0; q < 4; ++q) {
                    const int m = w * 4 + q;
                    if (m < 31) {
                        const float* src = h1p + (m * 16 + xr4) * 64 + b0 + xj;
                        __builtin_amdgcn_global_load_lds(src, &s_x[8000 + m * 256], 16, 0, 0);
                    }
                }
                if (w == 7 && l < 16) {   // rows 996..999 = h1 rows 496..499
                    const int r = 996 + (l >> 2);
                    const float4 v = *(const float4*)(h1p + (r - 500) * 64 + b0 + (l & 3) * 4);
                    *(float4*)&s_x[r * 16 + (l & 3) * 4] = v;
                }
            } else {
                #pragma unroll
                for (int q = 0; q < 8; ++q) {
                    const int m = w * 8 + q;
                    if (m < 62) {
                        const int k = m * 16 + xr4;
                        const float* src = (k < 500) ? (h1p + k * 64 + b0 + xj)
                                                     : (h2p + (k - 500) * 64 + b0 + xj);
                        __builtin_amdgcn_global_load_lds(src, &s_x[m * 256], 16, 0, 0);
                    }
                }
                if (w == 7 && l < 32) {   // rows 992..999 = h2 rows 492..499
                    const int r = 992 + (l >> 2);
                    const float4 v = *(const float4*)(h2p + (r - 500) * 64 + b0 + (l & 3) * 4);
                    *(float4*)&s_x[r * 16 + (l & 3) * 4] = v;
                }
            }
            // weight chunk 0 (wave-local rows)
            #pragma unroll
            for (int q = 0; q < 4; ++q) {
                const int m = w * 4 + q;
                const int rsrc = min(4 * m + wri, 999);
                __builtin_amdgcn_global_load_lds(Wm + (size_t)rsrc * 2000 + wcolg,
                                                 &s_w[0][m * 256], 16, 0, 0);
            }
            __syncthreads();   // x is cross-wave; one full drain per step

            float4 acc[8][2];
            #pragma unroll
            for (int cc = 0; cc < 8; ++cc) {
                acc[cc][0] = make_float4(0.f, 0.f, 0.f, 0.f);
                acc[cc][1] = make_float4(0.f, 0.f, 0.f, 0.f);
            }

            #pragma unroll
            for (int c = 0; c < 8; ++c) {
                if (c < 7) {   // prefetch chunk c+1; keep in flight (vmcnt(4))
                    #pragma unroll
                    for (int q = 0; q < 4; ++q) {
                        const int m = w * 4 + q;
                        const int rsrc = min((c + 1) * 128 + 4 * m + wri, 999);
                        __builtin_amdgcn_global_load_lds(Wm + (size_t)rsrc * 2000 + wcolg,
                                                         &s_w[(c + 1) & 1][m * 256], 16, 0, 0);
                    }
                    asm volatile("s_waitcnt vmcnt(4)" ::: "memory");
                } else {
                    asm volatile("s_waitcnt vmcnt(0)" ::: "memory");
                }
                __builtin_amdgcn_sched_barrier(0);
                const float* wb = s_w[c & 1];
                #pragma unroll
                for (int i = 0; i < 4; ++i) {
                    const int lrow = 16 * w + 4 * i + ks;
                    const float4 wA = *(const float4*)&wb[lrow * 64 + wc0];
                    const float4 wB = *(const float4*)&wb[lrow * 64 + wc1];
                    const float* xr = &s_x[(c * 128 + lrow) * 16 + xoff];
                    const float4 xA = *(const float4*)(xr);
                    const float4 xB = *(const float4*)(xr + 4);
#define ACCUM(CC, WS) \
    acc[CC][0].x = fmaf(WS, xA.x, acc[CC][0].x); \
    acc[CC][0].y = fmaf(WS, xA.y, acc[CC][0].y); \
    acc[CC][0].z = fmaf(WS, xA.z, acc[CC][0].z); \
    acc[CC][0].w = fmaf(WS, xA.w, acc[CC][0].w); \
    acc[CC][1].x = fmaf(WS, xB.x, acc[CC][1].x); \
    acc[CC][1].y = fmaf(WS, xB.y, acc[CC][1].y); \
    acc[CC][1].z = fmaf(WS, xB.z, acc[CC][1].z); \
    acc[CC][1].w = fmaf(WS, xB.w, acc[CC][1].w);
                    ACCUM(0, wA.x) ACCUM(1, wA.y) ACCUM(2, wA.z) ACCUM(3, wA.w)
                    ACCUM(4, wB.x) ACCUM(5, wB.y) ACCUM(6, wB.z) ACCUM(7, wB.w)
#undef ACCUM
                }
            }
            // ---- combine K-sublanes (f32 shfl tree over ks) ----
            #pragma unroll
            for (int cc = 0; cc < 8; ++cc) {
                #pragma unroll
                for (int j = 0; j < 2; ++j) {
                    float4& v = acc[cc][j];
                    v.x += __shfl_xor(v.x, 16, 64);
                    v.y += __shfl_xor(v.y, 16, 64);
                    v.z += __shfl_xor(v.z, 16, 64);
                    v.w += __shfl_xor(v.w, 16, 64);
                    v.x += __shfl_xor(v.x, 32, 64);
                    v.y += __shfl_xor(v.y, 32, 64);
                    v.z += __shfl_xor(v.z, 32, 64);
                    v.w += __shfl_xor(v.w, 32, 64);
                }
            }
            if (ks == 0) {   // write wave partials into own s_w[0] segment
                #pragma unroll
                for (int cc = 0; cc < 8; ++cc) {
                    const int cl = 8 * c8 + cc;
                    #pragma unroll
                    for (int j = 0; j < 2; ++j) {
                        const int pos = b2 * 8 + 4 * (j ^ (c8 & 1));
                        *(float4*)&s_w[0][w * 1024 + cl * 16 + pos] = acc[cc][j];
                    }
                }
            }
            __syncthreads();
            // ---- gates: f64 combine of 8 wave-partials + LSTM cell ----
            if (gth) {
                double z0 = 0, z1 = 0, z2 = 0, z3 = 0;
                #pragma unroll
                for (int q = 0; q < 8; ++q) {
                    const int base = q * 1024 + swb;
                    z0 += (double)s_w[0][base + (uu) * 16];
                    z1 += (double)s_w[0][base + (16 + uu) * 16];
                    z2 += (double)s_w[0][base + (32 + uu) * 16];
                    z3 += (double)s_w[0][base + (48 + uu) * 16];
                }
                z0 += (double)bg0; z1 += (double)bg1;
                z2 += (double)bg2; z3 += (double)bg3;
                const double gi = 1.0 / (1.0 + exp(-z0));
                const double gf = 1.0 / (1.0 + exp(-(z2 + 1.0)));
                const double go_ = 1.0 / (1.0 + exp(-z3));
                cstate = gf * cstate + gi * tanh(z1);
                houtT[u * 64 + b0 + gb] = (float)(go_ * tanh(cstate));
            }
        }
        ++ep;
        gbar(flags, gop, bid, tid, ep);
    }

    // ---------- dense head (f64), lastT = h2 at t=399 (phase 0) ----------
    const float* lastT = h2b;
    if (tid < 200) {
        int o = bid * 200 + tid;                 // 256*200 = 64*800
        int b = o / 800, j = o - b * 800;
        double acci = 0;
        for (int kk = 0; kk < 500; ++kk)
            acci += (double)lastT[kk * 64 + b] * (double)w1[(size_t)kk * 800 + j];
        acci += (double)bw1[j];
        d1p[b * 800 + j] = (float)fmax(acci, 0.0);
    }
    ++ep;
    gbar(flags, gop, bid, tid, ep);
    if (tid < 25) {
        int o = bid * 25 + tid;                  // 256*25 = 64*100
        int b = o / 100, j = o - b * 100;
        const float* dr = d1p + b * 800;
        double acci = 0;
        for (int kk = 0; kk < 800; ++kk)
            acci += (double)dr[kk] * (double)w2[(size_t)kk * 100 + j];
        acci += (double)bw2[j];
        d2p[b * 100 + j] = (float)fmax(acci, 0.0);
    }
    ++ep;
    gbar(flags, gop, bid, tid, ep);
    if (bid == 0 && tid < 128) {
        int b = tid >> 1, cc = tid & 1;
        const float* dr = d2p + b * 100;
        double acci = 0;
        for (int kk = 0; kk < 100; ++kk)
            acci += (double)dr[kk] * (double)wpm[kk * 2 + cc];
        acci += (double)bpv[cc];
        out[b * 2 + cc] = (float)acci;
    }
}

extern "C" void kernel_launch(void* const* d_in, const int* in_sizes, int n_in,
                              void* d_out, int out_size, void* d_ws, size_t ws_size,
                              hipStream_t stream) {
    const int* X = (const int*)d_in[0];
    const float* embed = (const float*)d_in[1];
    const float* k1 = (const float*)d_in[2];
    const float* b1 = (const float*)d_in[3];
    const float* k2 = (const float*)d_in[4];
    const float* b2 = (const float*)d_in[5];
    const float* w1 = (const float*)d_in[6];
    const float* bw1 = (const float*)d_in[7];
    const float* w2 = (const float*)d_in[8];
    const float* bw2 = (const float*)d_in[9];
    const float* wpm = (const float*)d_in[10];
    const float* bpv = (const float*)d_in[11];

    hipMemsetAsync(d_ws, 0, 512000, stream);
    hipMemsetAsync((char*)d_ws + OFF_FLG, 0, 16448, stream);

    rnn_all<<<NBLK, NTHR, 0, stream>>>(X, embed, k1, b1, k2, b2, w1, bw1,
                                       w2, bw2, wpm, bpv,
                                       (float*)d_out, (char*)d_ws);
}

// Round 6
// 7469.261 us; speedup vs baseline: 3.2459x; 3.2459x over previous
//
#include <hip/hip_runtime.h>

// RNNModel: 2-layer LSTM (B=64,T=400,E=H=500) + MLP head (800->100->2).
// Round 6: one kernel launch per grid-step (401 nodes in the captured graph),
// layers pipelined inside each launch (L0: t=s, L1: t=s-1). Kernel boundaries
// replace the hand-rolled cross-XCD grid barrier (dispatch acquire/release
// gives device-wide ordering + visibility). Step body = round 4's validated
// body (absmax 0.0); cell state c now lives in ws as f64 (round-1 scheme).

#define NTHR 512
#define Bn 64
#define Tn 400
#define Hn 500

#define OFF_H1 0            // float [2][500*64] transposed h1
#define OFF_H2 256000       // float [2][500*64] transposed h2
#define OFF_C1 512000       // double [500*64] c1 (index u*64+b)
#define OFF_C2 768000       // double [500*64] c2
#define OFF_D1 1024000      // float [64*800]
#define OFF_D2 1228800      // float [64*100]
#define WS_ZERO 1254400

extern "C" __global__ void __launch_bounds__(NTHR)
rnn_step(const int* __restrict__ X, const float* __restrict__ embed,
         const float* __restrict__ k1, const float* __restrict__ b1g,
         const float* __restrict__ k2, const float* __restrict__ b2g,
         char* __restrict__ ws, int s)
{
    __shared__ float s_x[16384];     // [k][16] transposed x (rows 0..1023)
    __shared__ float s_w[2][8192];   // dbuf [128 rows][64 cols]
    // partial buffer aliases s_x[0..8192) after compute

    float* h1b = (float*)(ws + OFF_H1);
    float* h2b = (float*)(ws + OFF_H2);

    const int bid = blockIdx.x;
    const int tid = threadIdx.x;
    const int rr_ = bid >> 3;
    const int slice = (bid & 7) * 8 + (rr_ >> 2);  // XCD-grouped duplicates
    const int btile = rr_ & 3;
    const int L = slice >> 5;
    const int ut = slice & 31;
    const int b0 = btile * 16;

    const bool active = L ? (s >= 1) : (s < Tn);
    if (!active) return;

    const int w = tid >> 6;          // wave
    const int l = tid & 63;
    const int cq = l & 15;           // col quad (4 cols)
    const int bp = l >> 4;           // batch quad (4 batches)

    const float* Wm = L ? k2 : k1;   // [1000][2000], col = g*500+u
    const float* bv = L ? b2g : b1g;
    double* cb = (double*)(ws + (L ? OFF_C2 : OFF_C1));

    // weight-stage lane constants
    const int wg = cq >> 2;
    const int wcol = wg * 500 + min(ut * 16 + 4 * (cq & 3), 496);
    const int wri = l >> 4;

    // x-stage lane constants
    const int xr4 = l >> 2;
    const int xj = (l & 3) * 4;

    // gate thread constants (tid<256): (batch gb, unit uu)
    const int uu = tid & 15;
    const int gb = tid >> 4;
    const int u = ut * 16 + uu;
    const bool gth = (tid < 256) && (u < Hn);
    const float bg0 = gth ? bv[u] : 0.f;
    const float bg1 = gth ? bv[500 + u] : 0.f;
    const float bg2 = gth ? bv[1000 + u] : 0.f;
    const float bg3 = gth ? bv[1500 + u] : 0.f;

    const int cur = s & 1, prv = cur ^ 1;
    const float* h1p = h1b + prv * 32000;
    const float* h2p = h2b + prv * 32000;
    float* houtT = (L ? h2b : h1b) + cur * 32000;

    const int t = L ? (s - 1) : s;
    // ---------- x staging (rows transposed [k][16]) ----------
    if (L == 0) {
        #pragma unroll
        for (int q = 0; q < 4; ++q) {   // h1prev -> rows 500.. (linear)
            const int m = w * 4 + q;
            const float* src = h1p + (m * 16 + xr4) * 64 + b0 + xj;
            __builtin_amdgcn_global_load_lds(src, &s_x[8000 + m * 256], 16, 0, 0);
        }
        const int eb = tid & 15;        // embed transpose rows 0..499
        const int q0 = tid >> 4;
        const float* er = embed + (size_t)X[(b0 + eb) * Tn + t] * 500;
        #pragma unroll
        for (int jj = 0; jj < 4; ++jj) {
            const int q = q0 + 32 * jj;
            if (q < 125) {
                const float4 v = *(const float4*)(er + 4 * q);
                float* d = &s_x[(4 * q) * 16 + eb];
                d[0] = v.x; d[16] = v.y; d[32] = v.z; d[48] = v.w;
            }
        }
    } else {
        #pragma unroll
        for (int q = 0; q < 8; ++q) {
            const int m = w * 8 + q;
            const int k = m * 16 + xr4;
            const float* src = (k < 500) ? (h1p + k * 64 + b0 + xj)
                                         : (h2p + (k - 500) * 64 + b0 + xj);
            __builtin_amdgcn_global_load_lds(src, &s_x[m * 256], 16, 0, 0);
        }
    }
    // ---------- weight chunk 0 ----------
    #pragma unroll
    for (int q = 0; q < 4; ++q) {
        const int m = w * 4 + q;
        const float* src = Wm + (size_t)(4 * m + wri) * 2000 + wcol;
        __builtin_amdgcn_global_load_lds(src, &s_w[0][m * 256], 16, 0, 0);
    }
    __syncthreads();

    float acc[4][4];
    #pragma unroll
    for (int a_ = 0; a_ < 4; ++a_) {
        acc[a_][0] = 0.f; acc[a_][1] = 0.f; acc[a_][2] = 0.f; acc[a_][3] = 0.f;
    }

    for (int c = 0; c < 8; ++c) {
        if (c < 7) {                      // prefetch chunk c+1
            const int k0n = (c + 1) * 128;
            const int nrn = (c < 6) ? 128 : 104;
            #pragma unroll
            for (int q = 0; q < 4; ++q) {
                const int m = w * 4 + q;
                const int rl = min(4 * m + wri, nrn - 1);
                const float* src = Wm + (size_t)(k0n + rl) * 2000 + wcol;
                __builtin_amdgcn_global_load_lds(src, &s_w[(c + 1) & 1][m * 256], 16, 0, 0);
            }
        }
        const int nr = (c < 7) ? 16 : 13;
        const int k0 = (c < 7) ? c * 128 : 896;
        const int r0 = w * nr;
        const float* wp = &s_w[c & 1][r0 * 64 + cq * 4];
        const float* xp = &s_x[(k0 + r0) * 16 + bp * 4];
        #pragma unroll 8
        for (int i = 0; i < nr; ++i) {
            const float4 wv = *(const float4*)(wp + i * 64);
            const float4 xv = *(const float4*)(xp + i * 16);
            acc[0][0] = fmaf(wv.x, xv.x, acc[0][0]);
            acc[0][1] = fmaf(wv.x, xv.y, acc[0][1]);
            acc[0][2] = fmaf(wv.x, xv.z, acc[0][2]);
            acc[0][3] = fmaf(wv.x, xv.w, acc[0][3]);
            acc[1][0] = fmaf(wv.y, xv.x, acc[1][0]);
            acc[1][1] = fmaf(wv.y, xv.y, acc[1][1]);
            acc[1][2] = fmaf(wv.y, xv.z, acc[1][2]);
            acc[1][3] = fmaf(wv.y, xv.w, acc[1][3]);
            acc[2][0] = fmaf(wv.z, xv.x, acc[2][0]);
            acc[2][1] = fmaf(wv.z, xv.y, acc[2][1]);
            acc[2][2] = fmaf(wv.z, xv.z, acc[2][2]);
            acc[2][3] = fmaf(wv.z, xv.w, acc[2][3]);
            acc[3][0] = fmaf(wv.w, xv.x, acc[3][0]);
            acc[3][1] = fmaf(wv.w, xv.y, acc[3][1]);
            acc[3][2] = fmaf(wv.w, xv.z, acc[3][2]);
            acc[3][3] = fmaf(wv.w, xv.w, acc[3][3]);
        }
        __syncthreads();   // drains chunk c+1 staging (m97 pattern)
    }
    // ---------- partials to s_x[0..8192) ----------
    #pragma unroll
    for (int ct = 0; ct < 4; ++ct) {
        *(float4*)&s_x[w * 1024 + (4 * cq + ct) * 16 + bp * 4] =
            make_float4(acc[ct][0], acc[ct][1], acc[ct][2], acc[ct][3]);
    }
    __syncthreads();
    // ---------- gates: f64 combine over 8 waves + LSTM cell ----------
    if (gth) {
        double z0 = 0, z1 = 0, z2 = 0, z3 = 0;
        #pragma unroll
        for (int q = 0; q < 8; ++q) {
            const int base = q * 1024 + uu * 16 + gb;
            z0 += (double)s_x[base];
            z1 += (double)s_x[base + 256];
            z2 += (double)s_x[base + 512];
            z3 += (double)s_x[base + 768];
        }
        z0 += (double)bg0; z1 += (double)bg1;
        z2 += (double)bg2; z3 += (double)bg3;
        const double gi = 1.0 / (1.0 + exp(-z0));
        const double gf = 1.0 / (1.0 + exp(-(z2 + 1.0)));
        const double go_ = 1.0 / (1.0 + exp(-z3));
        const int ci = u * 64 + b0 + gb;
        const double cnew = gf * cb[ci] + gi * tanh(z1);
        cb[ci] = cnew;
        houtT[ci] = (float)(go_ * tanh(cnew));
    }
}

// ---------- dense head (f64 accumulation), round-1-validated math ----------
extern "C" __global__ void __launch_bounds__(256)
head1(const char* __restrict__ ws_c, const float* __restrict__ w1,
      const float* __restrict__ bw1, char* __restrict__ ws)
{
    const float* lastT = (const float*)(ws_c + OFF_H2);  // h2 phase 0 (t=399)
    float* d1p = (float*)(ws + OFF_D1);
    const int o = blockIdx.x * 256 + threadIdx.x;        // 200 blocks
    if (o >= 51200) return;
    const int b = o / 800, j = o - b * 800;
    double acc = 0;
    for (int kk = 0; kk < 500; ++kk)
        acc += (double)lastT[kk * 64 + b] * (double)w1[(size_t)kk * 800 + j];
    acc += (double)bw1[j];
    d1p[b * 800 + j] = (float)fmax(acc, 0.0);
}

extern "C" __global__ void __launch_bounds__(256)
head2(const char* __restrict__ ws_c, const float* __restrict__ w2,
      const float* __restrict__ bw2, char* __restrict__ ws)
{
    const float* d1p = (const float*)(ws_c + OFF_D1);
    float* d2p = (float*)(ws + OFF_D2);
    const int o = blockIdx.x * 256 + threadIdx.x;        // 25 blocks
    if (o >= 6400) return;
    const int b = o / 100, j = o - b * 100;
    const float* dr = d1p + b * 800;
    double acc = 0;
    for (int kk = 0; kk < 800; ++kk)
        acc += (double)dr[kk] * (double)w2[(size_t)kk * 100 + j];
    acc += (double)bw2[j];
    d2p[b * 100 + j] = (float)fmax(acc, 0.0);
}

extern "C" __global__ void __launch_bounds__(128)
head3(const char* __restrict__ ws_c, const float* __restrict__ wpm,
      const float* __restrict__ bpv, float* __restrict__ out)
{
    const float* d2p = (const float*)(ws_c + OFF_D2);
    const int tid = threadIdx.x;                         // 1 block, 128 thr
    const int b = tid >> 1, cc = tid & 1;
    const float* dr = d2p + b * 100;
    double acc = 0;
    for (int kk = 0; kk < 100; ++kk)
        acc += (double)dr[kk] * (double)wpm[kk * 2 + cc];
    acc += (double)bpv[cc];
    out[b * 2 + cc] = (float)acc;
}

extern "C" void kernel_launch(void* const* d_in, const int* in_sizes, int n_in,
                              void* d_out, int out_size, void* d_ws, size_t ws_size,
                              hipStream_t stream) {
    const int* X = (const int*)d_in[0];
    const float* embed = (const float*)d_in[1];
    const float* k1 = (const float*)d_in[2];
    const float* b1 = (const float*)d_in[3];
    const float* k2 = (const float*)d_in[4];
    const float* b2 = (const float*)d_in[5];
    const float* w1 = (const float*)d_in[6];
    const float* bw1 = (const float*)d_in[7];
    const float* w2 = (const float*)d_in[8];
    const float* bw2 = (const float*)d_in[9];
    const float* wpm = (const float*)d_in[10];
    const float* bpv = (const float*)d_in[11];
    char* ws = (char*)d_ws;

    // zero h (both phases), c (f64), d1/d2 — captured: clean every replay
    hipMemsetAsync(d_ws, 0, WS_ZERO, stream);

    for (int s = 0; s <= Tn; ++s)
        rnn_step<<<256, NTHR, 0, stream>>>(X, embed, k1, b1, k2, b2, ws, s);

    head1<<<200, 256, 0, stream>>>(ws, w1, bw1, ws);
    head2<<<25, 256, 0, stream>>>(ws, w2, bw2, ws);
    head3<<<1, 128, 0, stream>>>(ws, wpm, bpv, (float*)d_out);
}